// Round 8
// baseline (527.884 us; speedup 1.0000x reference)
//
#include <hip/hip_runtime.h>
#include <hip/hip_bf16.h>

#define NNODES 200000
#define NEDGES 6400000
#define NFEAT  128
#define NH     16
#define NMLP   100
#define NCLS   27
#define NGRAPH 4096

#define BKTSH  8                       // bucket = dst >> 8  (256 nodes/bucket)
#define BKTW   256
#define NBKT   ((NNODES + BKTW - 1) / BKTW)   // 782
#define NBLKA  256                     // phase-A blocks (1024 threads each)
#define ABLK   1024
#define EPB    (NEDGES / NBLKA)        // 25000 edges per phase-A block
#define HSZ    (NBKT * NBLKA)          // 200192 histogram entries
#define SCANB  1024
#define NSCAN2 ((HSZ + SCANB - 1) / SCANB)   // 196

// ---------------------------------------------------------------------------
// Phase A1: per-block LDS histogram over coarse buckets (dst>>8) -> H[b][k]
__global__ __launch_bounds__(ABLK) void k_histA(const int* __restrict__ dst,
                                                int* __restrict__ H) {
    __shared__ int hist[NBKT];         // 3.1 KB
    int tid = threadIdx.x, k = blockIdx.x;
    for (int b = tid; b < NBKT; b += ABLK) hist[b] = 0;
    __syncthreads();
    int base = k * EPB;
    for (int i = tid; i < EPB; i += ABLK) {
        int d = __builtin_nontemporal_load(dst + base + i);
        atomicAdd(&hist[d >> BKTSH], 1);
    }
    __syncthreads();
    for (int b = tid; b < NBKT; b += ABLK) H[b * NBLKA + k] = hist[b];
}

// 3-kernel exclusive scan over H (HSZ elements), in place
__global__ __launch_bounds__(256) void k_scan_part(const int* __restrict__ A,
                                                   int* __restrict__ bsum) {
    __shared__ int sd[256];
    int tid = threadIdx.x;
    int i0 = blockIdx.x * SCANB + tid * 4;
    int s = 0;
    #pragma unroll
    for (int u = 0; u < 4; ++u) {
        int i = i0 + u;
        if (i < HSZ) s += A[i];
    }
    sd[tid] = s;
    __syncthreads();
    for (int off = 128; off > 0; off >>= 1) {
        if (tid < off) sd[tid] += sd[tid + off];
        __syncthreads();
    }
    if (tid == 0) bsum[blockIdx.x] = sd[0];
}

// single-block exclusive scan of the NSCAN2 block sums; also zeroes G
__global__ __launch_bounds__(256) void k_scan_top(int* __restrict__ bsum,
                                                  float* __restrict__ G) {
    float4* G4 = (float4*)G;
    int tid = threadIdx.x;
    #pragma unroll
    for (int t = 0; t < (NGRAPH * NH / 4) / 256; ++t)
        G4[tid + t * 256] = make_float4(0.f, 0.f, 0.f, 0.f);

    __shared__ int sd[256];
    int i0 = tid * 4;
    int c[4];
    #pragma unroll
    for (int u = 0; u < 4; ++u) {
        int i = i0 + u;
        c[u] = (i < NSCAN2) ? bsum[i] : 0;
    }
    int mysum = c[0] + c[1] + c[2] + c[3];
    sd[tid] = mysum;
    __syncthreads();
    for (int off = 1; off < 256; off <<= 1) {
        int v = (tid >= off) ? sd[tid - off] : 0;
        __syncthreads();
        sd[tid] += v;
        __syncthreads();
    }
    int base = sd[tid] - mysum;
    #pragma unroll
    for (int u = 0; u < 4; ++u) {
        int i = i0 + u;
        if (i < NSCAN2) { bsum[i] = base; base += c[u]; }
    }
}

__global__ __launch_bounds__(256) void k_scan_final(int* __restrict__ A,
                                                    const int* __restrict__ bsum) {
    __shared__ int sd[256];
    int tid = threadIdx.x;
    int i0 = blockIdx.x * SCANB + tid * 4;
    int c[4];
    #pragma unroll
    for (int u = 0; u < 4; ++u) {
        int i = i0 + u;
        c[u] = (i < HSZ) ? A[i] : 0;
    }
    int mysum = c[0] + c[1] + c[2] + c[3];
    sd[tid] = mysum;
    __syncthreads();
    for (int off = 1; off < 256; off <<= 1) {
        int v = (tid >= off) ? sd[tid - off] : 0;
        __syncthreads();
        sd[tid] += v;
        __syncthreads();
    }
    int base = bsum[blockIdx.x] + sd[tid] - mysum;
    #pragma unroll
    for (int u = 0; u < 4; ++u) {
        int i = i0 + u;
        if (i < HSZ) { A[i] = base; base += c[u]; }
    }
}

// Phase A2: scatter edges into bucket-grouped array P (packed (dst&255)<<18|src)
__global__ __launch_bounds__(ABLK) void k_scatterA(const int* __restrict__ src,
                                                   const int* __restrict__ dst,
                                                   const int* __restrict__ S,
                                                   int* __restrict__ P) {
    __shared__ int cnt[NBKT];          // 3.1 KB: running write ptr per bucket
    int tid = threadIdx.x, k = blockIdx.x;
    for (int b = tid; b < NBKT; b += ABLK) cnt[b] = S[b * NBLKA + k];
    __syncthreads();
    int base = k * EPB;
    for (int i = tid; i < EPB; i += ABLK) {
        int d = __builtin_nontemporal_load(dst + base + i);
        int s = __builtin_nontemporal_load(src + base + i);
        int pos = atomicAdd(&cnt[d >> BKTSH], 1);
        P[pos] = ((d & (BKTW - 1)) << 18) | s;   // src < 2^18
    }
}

// Phase B: one block per bucket (256 nodes) -> rp, dinv, colidx
__global__ __launch_bounds__(512) void k_csrB(const int* __restrict__ P,
                                              const int* __restrict__ S,
                                              int* __restrict__ rp,
                                              float* __restrict__ dinv,
                                              int* __restrict__ colidx) {
    __shared__ int deg[BKTW];
    __shared__ int wp[BKTW];
    __shared__ int sc[BKTW];
    __shared__ int se[2];
    int b = blockIdx.x, tid = threadIdx.x;
    if (tid == 0) {
        se[0] = S[b * NBLKA];
        se[1] = (b == NBKT - 1) ? NEDGES : S[(b + 1) * NBLKA];
    }
    if (tid < BKTW) deg[tid] = 0;
    __syncthreads();
    int start = se[0], end = se[1];

    for (int i = start + tid; i < end; i += 512)
        atomicAdd(&deg[P[i] >> 18], 1);
    __syncthreads();

    if (tid < BKTW) sc[tid] = deg[tid];
    __syncthreads();
    for (int off = 1; off < BKTW; off <<= 1) {
        int v = 0;
        if (tid < BKTW && tid >= off) v = sc[tid - off];
        __syncthreads();
        if (tid < BKTW) sc[tid] += v;
        __syncthreads();
    }
    if (tid < BKTW) {
        wp[tid] = start + sc[tid] - deg[tid];   // exclusive prefix
        int node = b * BKTW + tid;
        if (node < NNODES) {
            rp[node]   = wp[tid];
            dinv[node] = rsqrtf(1.f + (float)deg[tid]);
        }
    }
    if (b == 0 && tid == 0) rp[NNODES] = NEDGES;
    __syncthreads();

    for (int i = start + tid; i < end; i += 512) {
        int v = P[i];
        int pos = atomicAdd(&wp[v >> 18], 1);
        colidx[pos] = v & 0x3FFFF;
    }
}

// A1planes[jq][i][0..3] = dinv[i] * (x[i] @ W1)[jq*4..jq*4+3]  (plane-major)
#define GROWS 64
#define GPAD  129
__global__ __launch_bounds__(256) void k_gemm1(const float* __restrict__ x,
                                               const float* __restrict__ W1,
                                               const float* __restrict__ dinv,
                                               float* __restrict__ A1) {
    __shared__ float xt[GROWS * GPAD];       // 33 KB
    __shared__ float Ws[NFEAT * NH];         // 8 KB
    int tid = threadIdx.x;
    int r0 = blockIdx.x * GROWS;

    #pragma unroll
    for (int t = 0; t < (NFEAT * NH) / 256; ++t)   // 8
        Ws[tid + t * 256] = W1[tid + t * 256];

    const float4* xg = (const float4*)(x + (size_t)r0 * NFEAT);
    #pragma unroll
    for (int t = 0; t < (GROWS * NFEAT / 4) / 256; ++t) {  // 8
        int fi = tid + t * 256;              // float4 index within tile
        float4 v = xg[fi];
        int row = fi >> 5;                   // 32 float4 per row
        int c4  = fi & 31;
        float* p = &xt[row * GPAD + c4 * 4];
        p[0] = v.x; p[1] = v.y; p[2] = v.z; p[3] = v.w;
    }
    __syncthreads();

    int r  = tid >> 2;      // 0..63
    int jq = tid & 3;       // plane index
    float4 acc = make_float4(0.f, 0.f, 0.f, 0.f);
    #pragma unroll 8
    for (int k = 0; k < NFEAT; ++k) {
        float xv = xt[r * GPAD + k];
        float4 w = *(const float4*)&Ws[k * NH + jq * 4];
        acc.x += xv * w.x; acc.y += xv * w.y;
        acc.z += xv * w.z; acc.w += xv * w.w;
    }
    int n = r0 + r;
    float s = dinv[n];
    acc.x *= s; acc.y *= s; acc.z *= s; acc.w *= s;
    *(float4*)&A1[((size_t)jq * NNODES + n) * 4] = acc;
}

// Feature-sliced gather: group g = bid&3 processes plane g only.
// T[g][n] = A[g][n] + sum_{c in nbr(n)} A[g][c]
// 16 lanes/node: 4 edge-subgroups (e4) x 4 feature lanes (j).
__global__ __launch_bounds__(256) void k_gatherS(const float* __restrict__ Ain,
                                                 const int* __restrict__ rp,
                                                 const int* __restrict__ ci,
                                                 float* __restrict__ Tout) {
    int bid = blockIdx.x;
    int g   = bid & 3;                 // plane/group; XCD (bid%8) sees one g only
    int nb  = bid >> 2;
    int tid = threadIdx.x;
    int nl  = tid >> 4;                // 16 node-lanes per block
    int e4  = (tid >> 2) & 3;          // edge subgroup
    int j   = tid & 3;                 // feature within plane
    int n   = nb * 16 + nl;
    const float* A = Ain + (size_t)g * NNODES * 4;

    int r0 = rp[n], r1 = rp[n + 1];
    float acc = (e4 == 0) ? A[(size_t)n * 4 + j] : 0.f;   // self-loop term

    int k = r0 + e4;
    for (; k + 12 < r1; k += 16) {     // 4 edges in flight per subgroup
        int c0 = ci[k], c1 = ci[k + 4], c2 = ci[k + 8], c3 = ci[k + 12];
        float v0 = A[(size_t)c0 * 4 + j], v1 = A[(size_t)c1 * 4 + j];
        float v2 = A[(size_t)c2 * 4 + j], v3 = A[(size_t)c3 * 4 + j];
        acc += (v0 + v1) + (v2 + v3);
    }
    for (; k < r1; k += 4) acc += A[(size_t)ci[k] * 4 + j];

    acc += __shfl_xor(acc, 4);         // reduce over edge subgroups
    acc += __shfl_xor(acc, 8);
    if (e4 == 0) Tout[((size_t)g * NNODES + n) * 4 + j] = acc;
}

// dense mid layer: h = relu(dinv*T1 + b1); A2 = dinv*(h @ W2)  (in-place on T1)
__global__ __launch_bounds__(256) void k_mid(float* __restrict__ T1,   // planeB, in/out
                                             const float* __restrict__ dinv,
                                             const float* __restrict__ b1,
                                             const float* __restrict__ W2) {
    __shared__ float W2s[NH * NH];
    __shared__ float b1s[NH];
    int tid = threadIdx.x;
    if (tid < NH * NH) W2s[tid] = W2[tid];
    if (tid < NH)      b1s[tid] = b1[tid];
    __syncthreads();

    int n = blockIdx.x * 256 + tid;
    if (n >= NNODES) return;
    float s = dinv[n];

    float h[NH];
    #pragma unroll
    for (int g = 0; g < 4; ++g) {
        float4 v = *(const float4*)&T1[((size_t)g * NNODES + n) * 4];
        h[g * 4 + 0] = v.x; h[g * 4 + 1] = v.y;
        h[g * 4 + 2] = v.z; h[g * 4 + 3] = v.w;
    }
    #pragma unroll
    for (int jj = 0; jj < NH; ++jj) h[jj] = fmaxf(h[jj] * s + b1s[jj], 0.f);

    float o[NH];
    #pragma unroll
    for (int jj = 0; jj < NH; ++jj) o[jj] = 0.f;
    #pragma unroll
    for (int k = 0; k < NH; ++k) {
        float hk = h[k];
        const float* wrow = &W2s[k * NH];
        #pragma unroll
        for (int jj = 0; jj < NH; ++jj) o[jj] += hk * wrow[jj];
    }
    #pragma unroll
    for (int g = 0; g < 4; ++g) {
        float4 v = make_float4(o[g * 4 + 0] * s, o[g * 4 + 1] * s,
                               o[g * 4 + 2] * s, o[g * 4 + 3] * s);
        *(float4*)&T1[((size_t)g * NNODES + n) * 4] = v;
    }
}

// pool: h2 = dinv*T2 + b2; G[batch[n]] += h2
__global__ __launch_bounds__(256) void k_pool(const float* __restrict__ T2,
                                              const float* __restrict__ dinv,
                                              const float* __restrict__ b2,
                                              const int* __restrict__ batch,
                                              float* __restrict__ G) {
    __shared__ float b2s[NH];
    int tid = threadIdx.x;
    if (tid < NH) b2s[tid] = b2[tid];
    __syncthreads();

    int nl = tid >> 4, j = tid & 15;
    int n  = blockIdx.x * 16 + nl;
    float v = T2[(((size_t)(j >> 2)) * NNODES + n) * 4 + (j & 3)];
    float h2 = v * dinv[n] + b2s[j];
    atomicAdd(&G[(size_t)batch[n] * NH + j], h2);
}

// head: per graph: relu(G) -> MLP1 -> relu -> MLP2 -> out
__global__ __launch_bounds__(128) void k_head(const float* __restrict__ G,
                                              const float* __restrict__ Wl1,
                                              const float* __restrict__ bl1,
                                              const float* __restrict__ Wl2,
                                              const float* __restrict__ bl2,
                                              float* __restrict__ out) {
    __shared__ float gv[NH];
    __shared__ float g1[NMLP];
    int g = blockIdx.x, tid = threadIdx.x;

    if (tid < NH) gv[tid] = fmaxf(G[(size_t)g * NH + tid], 0.f);
    __syncthreads();

    if (tid < NMLP) {
        float a = bl1[tid];
        #pragma unroll
        for (int k = 0; k < NH; ++k) a += gv[k] * Wl1[k * NMLP + tid];
        g1[tid] = fmaxf(a, 0.f);
    }
    __syncthreads();

    if (tid < NCLS) {
        float a = bl2[tid];
        for (int k = 0; k < NMLP; ++k) a += g1[k] * Wl2[k * NCLS + tid];
        out[(size_t)g * NCLS + tid] = a;
    }
}

// ---------------------------------------------------------------------------
extern "C" void kernel_launch(void* const* d_in, const int* in_sizes, int n_in,
                              void* d_out, int out_size, void* d_ws, size_t ws_size,
                              hipStream_t stream) {
    const float* x     = (const float*)d_in[0];
    const int*   edge  = (const int*)d_in[1];   // [2, E] flat: src then dst
    const int*   batch = (const int*)d_in[2];
    const float* W1    = (const float*)d_in[3];
    const float* b1    = (const float*)d_in[4];
    const float* W2    = (const float*)d_in[5];
    const float* b2    = (const float*)d_in[6];
    const float* Wl1   = (const float*)d_in[7];
    const float* bl1   = (const float*)d_in[8];
    const float* Wl2   = (const float*)d_in[9];
    const float* bl2   = (const float*)d_in[10];
    float*       out   = (float*)d_out;

    // workspace layout (256B aligned)
    char* ws = (char*)d_ws;
    size_t cur = 0;
    auto alloc = [&](size_t bytes) {
        void* p = ws + cur;
        cur += (bytes + 255) & ~(size_t)255;
        return p;
    };
    int*   H      = (int*)  alloc((size_t)HSZ * 4);            // 801 KB (becomes S)
    int*   bsum   = (int*)  alloc((size_t)NSCAN2 * 4);
    int*   P      = (int*)  alloc((size_t)NEDGES * 4);         // 25.6 MB packed pairs
    int*   colidx = (int*)  alloc((size_t)NEDGES * 4);         // 25.6 MB
    int*   rp     = (int*)  alloc((size_t)(NNODES + 1) * 4);
    float* dinv   = (float*)alloc((size_t)NNODES * 4);
    float* planeA = (float*)alloc((size_t)NNODES * NH * 4);    // A1, later T2
    float* planeB = (float*)alloc((size_t)NNODES * NH * 4);    // T1, in-place A2
    float* G      = (float*)alloc((size_t)NGRAPH * NH * 4);

    const int* src = edge;
    const int* dst = edge + NEDGES;

    int nb_gemm = NNODES / GROWS;                     // 3125
    int nb_gath = (NNODES / 16) * 4;                  // 50000 (4 feature groups)
    int nb_pool = NNODES / 16;                        // 12500
    int nb_mid  = (NNODES + 255) / 256;               // 782

    k_histA     <<<NBLKA,  ABLK, 0, stream>>>(dst, H);
    k_scan_part <<<NSCAN2, 256, 0, stream>>>(H, bsum);
    k_scan_top  <<<1,      256, 0, stream>>>(bsum, G);
    k_scan_final<<<NSCAN2, 256, 0, stream>>>(H, bsum);
    k_scatterA  <<<NBLKA,  ABLK, 0, stream>>>(src, dst, H, P);
    k_csrB      <<<NBKT,   512, 0, stream>>>(P, H, rp, dinv, colidx);
    k_gemm1     <<<nb_gemm, 256, 0, stream>>>(x, W1, dinv, planeA);
    k_gatherS   <<<nb_gath, 256, 0, stream>>>(planeA, rp, colidx, planeB);
    k_mid       <<<nb_mid,  256, 0, stream>>>(planeB, dinv, b1, W2);
    k_gatherS   <<<nb_gath, 256, 0, stream>>>(planeB, rp, colidx, planeA);
    k_pool      <<<nb_pool, 256, 0, stream>>>(planeA, dinv, b2, batch, G);
    k_head      <<<NGRAPH, 128, 0, stream>>>(G, Wl1, bl1, Wl2, bl2, out);
}